// Round 1
// baseline (36452.371 us; speedup 1.0000x reference)
//
#include <hip/hip_runtime.h>
#include <math.h>

#define T_SEQ 1024
#define B_SZ  128
#define I_SZ  256
#define H_SZ  512
#define G_SZ  1536  // 3*H

__device__ __forceinline__ float sigmoidf_(float x) {
    return 1.0f / (1.0f + expf(-x));
}

// ---------------------------------------------------------------------------
// Kernel 0: transpose weights into [K][G] layout (coalesced col-streaming in
// the matvec kernels) and broadcast h0 into the per-batch h buffer.
// ---------------------------------------------------------------------------
__global__ void setup_kernel(const float* __restrict__ w_ih,
                             const float* __restrict__ w_hh,
                             const float* __restrict__ h0,
                             float* __restrict__ wT_ih,   // [I][G]
                             float* __restrict__ wT_hh,   // [H][G]
                             float* __restrict__ h_buf) { // [B][H]
    const int total_hh = G_SZ * H_SZ;   // 786432
    const int total_ih = G_SZ * I_SZ;   // 393216
    const int total_h  = B_SZ * H_SZ;   // 65536
    const int total = total_hh + total_ih + total_h;
    for (int i = blockIdx.x * blockDim.x + threadIdx.x; i < total;
         i += gridDim.x * blockDim.x) {
        if (i < total_hh) {
            int g = i / H_SZ, k = i % H_SZ;
            wT_hh[k * G_SZ + g] = w_hh[i];
        } else if (i < total_hh + total_ih) {
            int j = i - total_hh;
            int g = j / I_SZ, k = j % I_SZ;
            wT_ih[k * G_SZ + g] = w_ih[j];
        } else {
            int j = i - total_hh - total_ih;
            h_buf[j] = h0[j % H_SZ];
        }
    }
}

// ---------------------------------------------------------------------------
// Kernel 1: input projection for a chunk of time steps.
// gi[(t-t0)*B + b][g] = sum_i x[b][t][i] * w_ih[g][i] + b_ih[g]
// Tiled f32 GEMM: 64x64 tile per 256-thread block, 4x4 per thread, K-step 16.
// ---------------------------------------------------------------------------
__global__ __launch_bounds__(256)
void proj_kernel(const float* __restrict__ x,      // [B][T][I]
                 const float* __restrict__ wT_ih,  // [I][G]
                 const float* __restrict__ b_ih,   // [G]
                 float* __restrict__ gi,           // [tc*B][G]
                 int t0) {
    const int m0 = blockIdx.x * 64;
    const int n0 = blockIdx.y * 64;
    const int tid = threadIdx.x;
    const int tx = tid & 15;       // 0..15 -> N
    const int ty = tid >> 4;       // 0..15 -> M

    __shared__ float As[16][64];   // [k][m]
    __shared__ float Bs[16][64];   // [k][n]

    float acc[4][4] = {};

    for (int k0 = 0; k0 < I_SZ; k0 += 16) {
        // A tile: thread -> row m = tid/4, 4 consecutive k via float4
        {
            int m  = tid >> 2;
            int kq = (tid & 3) * 4;
            int mm = m0 + m;
            int b  = mm & (B_SZ - 1);
            int t  = t0 + (mm >> 7);      // mm / 128
            const float* arow = x + ((size_t)b * T_SEQ + t) * I_SZ + k0 + kq;
            float4 v = *reinterpret_cast<const float4*>(arow);
            As[kq + 0][m] = v.x; As[kq + 1][m] = v.y;
            As[kq + 2][m] = v.z; As[kq + 3][m] = v.w;
        }
        // B tile: thread -> k = tid/16, 4 consecutive n via float4 (coalesced)
        {
            int k = tid >> 4;
            int n = (tid & 15) * 4;
            float4 v = *reinterpret_cast<const float4*>(
                wT_ih + (size_t)(k0 + k) * G_SZ + n0 + n);
            *reinterpret_cast<float4*>(&Bs[k][n]) = v;
        }
        __syncthreads();
        #pragma unroll
        for (int kk = 0; kk < 16; ++kk) {
            float a[4], bb[4];
            #pragma unroll
            for (int i = 0; i < 4; ++i) a[i] = As[kk][ty * 4 + i];
            #pragma unroll
            for (int j = 0; j < 4; ++j) bb[j] = Bs[kk][tx * 4 + j];
            #pragma unroll
            for (int i = 0; i < 4; ++i)
                #pragma unroll
                for (int j = 0; j < 4; ++j)
                    acc[i][j] = fmaf(a[i], bb[j], acc[i][j]);
        }
        __syncthreads();
    }

    const int n = n0 + tx * 4;
    float4 bv = *reinterpret_cast<const float4*>(b_ih + n);
    #pragma unroll
    for (int i = 0; i < 4; ++i) {
        int m = m0 + ty * 4 + i;
        float4 v;
        v.x = acc[i][0] + bv.x;
        v.y = acc[i][1] + bv.y;
        v.z = acc[i][2] + bv.z;
        v.w = acc[i][3] + bv.w;
        *reinterpret_cast<float4*>(gi + (size_t)m * G_SZ + n) = v;
    }
}

// ---------------------------------------------------------------------------
// Kernel 2: sequential recurrence over a chunk of steps.
// One block per batch element -> NO inter-block synchronization needed.
// h kept in LDS. Thread tid owns gate columns {tid, tid+256} of each of the
// three gates (cols tid+256*q, q=0..5 of the 1536-wide gh), which together
// form the complete update for h-columns {tid, tid+256}.
// Weight reads: wT_hh[k*1536 + tid + 256*q] -> fully coalesced across lanes,
// identical across the 128 blocks -> served from L2.
// ---------------------------------------------------------------------------
__global__ __launch_bounds__(256)
void rnn_kernel(const float* __restrict__ gi,     // [tc*B][G]
                const float* __restrict__ wT_hh,  // [H][G]
                const float* __restrict__ b_hh,   // [G]
                float* __restrict__ h_buf,        // [B][H]
                float* __restrict__ out,          // [B][T][H] then [B][H]
                int t0, int tc) {
    const int b   = blockIdx.x;
    const int tid = threadIdx.x;

    __shared__ float h_lds[H_SZ];
    h_lds[tid]       = h_buf[b * H_SZ + tid];
    h_lds[tid + 256] = h_buf[b * H_SZ + tid + 256];
    __syncthreads();

    // biases are loop-invariant
    const float bh_r0 = b_hh[tid];
    const float bh_r1 = b_hh[tid + 256];
    const float bh_z0 = b_hh[tid + 512];
    const float bh_z1 = b_hh[tid + 768];
    const float bh_n0 = b_hh[tid + 1024];
    const float bh_n1 = b_hh[tid + 1280];

    for (int tt = 0; tt < tc; ++tt) {
        float acc[6] = {0.f, 0.f, 0.f, 0.f, 0.f, 0.f};
        #pragma unroll 4
        for (int k = 0; k < H_SZ; ++k) {
            float hk = h_lds[k];
            const float* wr = wT_hh + (size_t)k * G_SZ + tid;
            #pragma unroll
            for (int q = 0; q < 6; ++q)
                acc[q] = fmaf(wr[q * 256], hk, acc[q]);
        }

        const float* girow = gi + ((size_t)tt * B_SZ + b) * G_SZ + tid;
        float gir0 = girow[0],    gir1 = girow[256];
        float giz0 = girow[512],  giz1 = girow[768];
        float gin0 = girow[1024], gin1 = girow[1280];

        float r0 = sigmoidf_(gir0 + acc[0] + bh_r0);
        float r1 = sigmoidf_(gir1 + acc[1] + bh_r1);
        float z0 = sigmoidf_(giz0 + acc[2] + bh_z0);
        float z1 = sigmoidf_(giz1 + acc[3] + bh_z1);
        float n0 = tanhf(gin0 + r0 * (acc[4] + bh_n0));
        float n1 = tanhf(gin1 + r1 * (acc[5] + bh_n1));

        float h0o = h_lds[tid], h1o = h_lds[tid + 256];
        float hn0 = (1.f - z0) * n0 + z0 * h0o;
        float hn1 = (1.f - z1) * n1 + z1 * h1o;
        hn0 = fminf(fmaxf(hn0, -5.f), 5.f);
        hn1 = fminf(fmaxf(hn1, -5.f), 5.f);

        __syncthreads();             // all reads of old h done
        h_lds[tid]       = hn0;
        h_lds[tid + 256] = hn1;
        __syncthreads();             // new h visible before next iteration

        size_t obase = ((size_t)b * T_SEQ + (t0 + tt)) * H_SZ;
        out[obase + tid]       = hn0;
        out[obase + tid + 256] = hn1;
    }

    h_buf[b * H_SZ + tid]       = h_lds[tid];
    h_buf[b * H_SZ + tid + 256] = h_lds[tid + 256];
    if (t0 + tc == T_SEQ) {
        size_t hl = (size_t)B_SZ * T_SEQ * H_SZ + (size_t)b * H_SZ;
        out[hl + tid]       = h_lds[tid];
        out[hl + tid + 256] = h_lds[tid + 256];
    }
}

// ---------------------------------------------------------------------------
extern "C" void kernel_launch(void* const* d_in, const int* in_sizes, int n_in,
                              void* d_out, int out_size, void* d_ws, size_t ws_size,
                              hipStream_t stream) {
    const float* x    = (const float*)d_in[0];
    const float* h0   = (const float*)d_in[1];
    const float* w_ih = (const float*)d_in[2];
    const float* w_hh = (const float*)d_in[3];
    const float* b_ih = (const float*)d_in[4];
    const float* b_hh = (const float*)d_in[5];
    float* out = (float*)d_out;

    float* wT_hh = (float*)d_ws;                 // 512*1536 f32 = 3 MB
    float* wT_ih = wT_hh + H_SZ * G_SZ;          // 256*1536 f32 = 1.5 MB
    float* h_buf = wT_ih + I_SZ * G_SZ;          // 128*512 f32
    float* gi    = h_buf + B_SZ * H_SZ;          // chunked [tc*B][G]

    const size_t fixed_bytes =
        ((size_t)H_SZ * G_SZ + (size_t)I_SZ * G_SZ + (size_t)B_SZ * H_SZ) * sizeof(float);
    const size_t gi_step = (size_t)B_SZ * G_SZ * sizeof(float);  // per time step

    int tc_max = 1;
    if (ws_size > fixed_bytes) {
        size_t fit = (ws_size - fixed_bytes) / gi_step;
        tc_max = (int)(fit > T_SEQ ? T_SEQ : fit);
        if (tc_max < 1) tc_max = 1;
    }

    setup_kernel<<<1216, 1024, 0, stream>>>(w_ih, w_hh, h0, wT_ih, wT_hh, h_buf);

    for (int t0 = 0; t0 < T_SEQ; t0 += tc_max) {
        int tc = (tc_max < T_SEQ - t0) ? tc_max : (T_SEQ - t0);
        dim3 pgrid(tc * 2, G_SZ / 64);   // (tc*128/64, 24)
        proj_kernel<<<pgrid, 256, 0, stream>>>(x, wT_ih, b_ih, gi, t0);
        rnn_kernel<<<128, 256, 0, stream>>>(gi, wT_hh, b_hh, h_buf, out, t0, tc);
    }
}

// Round 2
// 30807.797 us; speedup vs baseline: 1.1832x; 1.1832x over previous
//
#include <hip/hip_runtime.h>
#include <math.h>

#define T_SEQ 1024
#define B_SZ  128
#define I_SZ  256
#define H_SZ  512
#define G_SZ  1536  // 3*H

#define NBS   8    // batch slices
#define MB    16   // batch per block
#define NHS   16   // h slices
#define HB    32   // h cols per block
#define GB    96   // gate cols per block (3*HB)
#define NTHR  384  // 6 waves
#define CLUSTER 16 // blocks sharing a batch slice

typedef _Float16 f16;
typedef _Float16 half8 __attribute__((ext_vector_type(8)));
typedef float f32x4 __attribute__((ext_vector_type(4)));

// ---------------------------------------------------------------------------
// Setup: wT_ih f32 [I][G] for proj; w_hh -> f16 per-block slices [hs][96][512];
// h0 -> f16 broadcast buffer; zero cluster counters.
// ---------------------------------------------------------------------------
__global__ void setup_kernel(const float* __restrict__ w_ih,
                             const float* __restrict__ w_hh,
                             const float* __restrict__ h0,
                             float* __restrict__ wT_ih,
                             f16* __restrict__ wf16,
                             f16* __restrict__ hbuf0,
                             unsigned int* __restrict__ ctr) {
    const int i0 = blockIdx.x * blockDim.x + threadIdx.x;
    const int stride = gridDim.x * blockDim.x;
    for (int i = i0; i < I_SZ * G_SZ; i += stride) {
        int g = i / I_SZ, k = i % I_SZ;
        wT_ih[k * G_SZ + g] = w_ih[i];
    }
    for (int i = i0; i < NHS * GB * H_SZ; i += stride) {
        int hs  = i / (GB * H_SZ);
        int rem = i % (GB * H_SZ);
        int gl = rem / H_SZ, k = rem % H_SZ;
        int gate = gl >> 5, c = gl & 31;
        int gg = gate * H_SZ + hs * HB + c;
        wf16[i] = (f16)w_hh[gg * H_SZ + k];
    }
    for (int i = i0; i < B_SZ * H_SZ; i += stride) {
        hbuf0[i] = (f16)h0[i % H_SZ];
    }
    if (i0 < NBS * 32) ctr[i0] = 0;
}

// ---------------------------------------------------------------------------
// Input projection GEMM (f32), unchanged from the passing round-1 kernel.
// gi[(t*B + b)][g] = sum_i x[b][t][i] * w_ih[g][i] + b_ih[g]
// ---------------------------------------------------------------------------
__global__ __launch_bounds__(256)
void proj_kernel(const float* __restrict__ x,
                 const float* __restrict__ wT_ih,
                 const float* __restrict__ b_ih,
                 float* __restrict__ gi,
                 int t0) {
    const int m0 = blockIdx.x * 64;
    const int n0 = blockIdx.y * 64;
    const int tid = threadIdx.x;
    const int tx = tid & 15;
    const int ty = tid >> 4;

    __shared__ float As[16][64];
    __shared__ float Bs[16][64];

    float acc[4][4] = {};

    for (int k0 = 0; k0 < I_SZ; k0 += 16) {
        {
            int m  = tid >> 2;
            int kq = (tid & 3) * 4;
            int mm = m0 + m;
            int b  = mm & (B_SZ - 1);
            int t  = t0 + (mm >> 7);
            const float* arow = x + ((size_t)b * T_SEQ + t) * I_SZ + k0 + kq;
            float4 v = *reinterpret_cast<const float4*>(arow);
            As[kq + 0][m] = v.x; As[kq + 1][m] = v.y;
            As[kq + 2][m] = v.z; As[kq + 3][m] = v.w;
        }
        {
            int k = tid >> 4;
            int n = (tid & 15) * 4;
            float4 v = *reinterpret_cast<const float4*>(
                wT_ih + (size_t)(k0 + k) * G_SZ + n0 + n);
            *reinterpret_cast<float4*>(&Bs[k][n]) = v;
        }
        __syncthreads();
        #pragma unroll
        for (int kk = 0; kk < 16; ++kk) {
            float a[4], bb[4];
            #pragma unroll
            for (int i = 0; i < 4; ++i) a[i] = As[kk][ty * 4 + i];
            #pragma unroll
            for (int j = 0; j < 4; ++j) bb[j] = Bs[kk][tx * 4 + j];
            #pragma unroll
            for (int i = 0; i < 4; ++i)
                #pragma unroll
                for (int j = 0; j < 4; ++j)
                    acc[i][j] = fmaf(a[i], bb[j], acc[i][j]);
        }
        __syncthreads();
    }

    const int n = n0 + tx * 4;
    float4 bv = *reinterpret_cast<const float4*>(b_ih + n);
    #pragma unroll
    for (int i = 0; i < 4; ++i) {
        int m = m0 + ty * 4 + i;
        float4 v;
        v.x = acc[i][0] + bv.x;
        v.y = acc[i][1] + bv.y;
        v.z = acc[i][2] + bv.z;
        v.w = acc[i][3] + bv.w;
        *reinterpret_cast<float4*>(gi + (size_t)m * G_SZ + n) = v;
    }
}

// ---------------------------------------------------------------------------
// Persistent GRU recurrence. 128 blocks = 8 batch-slices x 16 h-slices.
// Weights stationary in LDS (98 KB f16, XOR-swizzled [g][k]).
// Per-cluster (16-block) monotonic-counter barrier per step; h exchanged as
// f16 via double-buffered global buffers; f32 h master kept block-local.
// ---------------------------------------------------------------------------
__global__ __launch_bounds__(NTHR, 1)
void gru_persist(const float* __restrict__ gi,
                 const f16* __restrict__ wf16,
                 const float* __restrict__ h0,
                 const float* __restrict__ b_hh,
                 f16* __restrict__ hbuf0,
                 f16* __restrict__ hbuf1,
                 unsigned int* __restrict__ ctr,
                 float* __restrict__ out) {
    const int bs  = blockIdx.x & (NBS - 1);
    const int hs  = blockIdx.x >> 3;
    const int tid = threadIdx.x;

    __shared__ __align__(16) unsigned char w_lds[GB * H_SZ * 2];  // 98304
    __shared__ __align__(16) unsigned char h_lds[MB * H_SZ * 2];  // 16384
    __shared__ float act_r[MB][HB];
    __shared__ float act_z[MB][HB];
    __shared__ float act_hn[MB][HB];
    __shared__ float act_in[MB][HB];
    __shared__ float h_master[MB][HB];

    // ---- load weight slice into LDS once (swizzled [g][k]) ----
    {
        const f16* wsrc = wf16 + (size_t)hs * GB * H_SZ;
        for (int i = tid; i < GB * H_SZ / 8; i += NTHR) {  // 6144 x 16B
            int g = i >> 6, k8 = i & 63;
            float4 v = *reinterpret_cast<const float4*>(wsrc + g * H_SZ + k8 * 8);
            unsigned addr = ((unsigned)(g * 1024 + k8 * 16)) ^ (((unsigned)(g & 7)) << 4);
            *reinterpret_cast<float4*>(w_lds + addr) = v;
        }
    }
    // ---- init f32 h master from h0 ----
    for (int i = tid; i < MB * HB; i += NTHR) {
        int b = i >> 5, c = i & 31;
        h_master[b][c] = h0[hs * HB + c];
    }
    __syncthreads();

    const int wid  = tid >> 6;
    const int lane = tid & 63;
    const int gate = wid >> 1;      // 0=r, 1=z, 2=n
    const int sub  = wid & 1;
    const int col  = lane & 15;
    const int krow = lane >> 4;     // 0..3
    const int c_local = sub * 16 + col;       // 0..31 within h-slice
    const int g_row   = gate * 32 + c_local;  // row in w_lds
    const int g_glob  = gate * H_SZ + hs * HB + c_local;
    const float bias  = b_hh[g_glob];

    const unsigned a_base = (unsigned)(col * 1024 + krow * 16);
    const unsigned a_swz  = ((unsigned)(col & 7)) << 4;
    const unsigned b_base = (unsigned)(g_row * 1024 + krow * 16);
    const unsigned b_swz  = ((unsigned)(g_row & 7)) << 4;

    unsigned int* myctr = ctr + bs * 32;  // counters 128B apart

    for (int t = 0; t < T_SEQ; ++t) {
        const f16* hin = (t & 1) ? hbuf1 : hbuf0;
        f16*      hout = (t & 1) ? hbuf0 : hbuf1;

        // stage h (f16) for this batch slice into LDS (swizzled [b][k])
        for (int i = tid; i < MB * H_SZ / 8; i += NTHR) {  // 1024 x 16B
            int b = i >> 6, k8 = i & 63;
            float4 v = *reinterpret_cast<const float4*>(
                hin + (size_t)(bs * MB + b) * H_SZ + k8 * 8);
            unsigned addr = ((unsigned)(b * 1024 + k8 * 16)) ^ (((unsigned)(b & 7)) << 4);
            *reinterpret_cast<float4*>(h_lds + addr) = v;
        }

        // gi loads issued early (independent of staged h)
        float giv[4];
        {
            const float* gp = gi + ((size_t)t * B_SZ + bs * MB) * G_SZ + g_glob;
            #pragma unroll
            for (int r = 0; r < 4; ++r)
                giv[r] = gp[(size_t)(krow * 4 + r) * G_SZ];
        }

        __syncthreads();

        // gh tile: 16 batch x 16 cols, K=512
        f32x4 acc = {0.f, 0.f, 0.f, 0.f};
        #pragma unroll
        for (int kk = 0; kk < 16; ++kk) {
            half8 av = *reinterpret_cast<const half8*>(h_lds + ((a_base + kk * 64) ^ a_swz));
            half8 bv = *reinterpret_cast<const half8*>(w_lds + ((b_base + kk * 64) ^ b_swz));
            acc = __builtin_amdgcn_mfma_f32_16x16x32_f16(av, bv, acc, 0, 0, 0);
        }

        // per-gate activation, staged to LDS
        if (gate == 0) {
            #pragma unroll
            for (int r = 0; r < 4; ++r) {
                int b = krow * 4 + r;
                act_r[b][c_local] = 1.f / (1.f + __expf(-(acc[r] + bias + giv[r])));
            }
        } else if (gate == 1) {
            #pragma unroll
            for (int r = 0; r < 4; ++r) {
                int b = krow * 4 + r;
                act_z[b][c_local] = 1.f / (1.f + __expf(-(acc[r] + bias + giv[r])));
            }
        } else {
            #pragma unroll
            for (int r = 0; r < 4; ++r) {
                int b = krow * 4 + r;
                act_hn[b][c_local] = acc[r] + bias;   // hn pre-act (gets r* later)
                act_in[b][c_local] = giv[r];          // inn
            }
        }
        __syncthreads();

        // combine: 512 outputs over threads 0..255 (2 each)
        if (tid < 256) {
            #pragma unroll
            for (int v = 0; v < 2; ++v) {
                int idx = tid + v * 256;
                int b = idx >> 5, c = idx & 31;
                float r = act_r[b][c], z = act_z[b][c];
                float a = act_in[b][c] + r * act_hn[b][c];
                float n = 1.f - 2.f / (__expf(2.f * a) + 1.f);  // tanh
                float ho = h_master[b][c];
                float hn2 = (1.f - z) * n + z * ho;
                hn2 = fminf(fmaxf(hn2, -5.f), 5.f);
                h_master[b][c] = hn2;
                int bg = bs * MB + b;
                int hg = hs * HB + c;
                out[((size_t)bg * T_SEQ + t) * H_SZ + hg] = hn2;
                hout[(size_t)bg * H_SZ + hg] = (f16)hn2;
                if (t == T_SEQ - 1)
                    out[(size_t)B_SZ * T_SEQ * H_SZ + (size_t)bg * H_SZ + hg] = hn2;
            }
        }
        __threadfence();     // make h_f16 writes agent-visible
        __syncthreads();
        if (tid == 0) {
            __hip_atomic_fetch_add(myctr, 1u, __ATOMIC_RELEASE, __HIP_MEMORY_SCOPE_AGENT);
            const unsigned target = (unsigned)(CLUSTER * (t + 1));
            int guard = 0;
            while (__hip_atomic_load(myctr, __ATOMIC_RELAXED, __HIP_MEMORY_SCOPE_AGENT) < target) {
                __builtin_amdgcn_s_sleep(1);
                if (++guard > 100000) break;   // safety escape (never in practice)
            }
        }
        __syncthreads();
        __threadfence();     // acquire: invalidate stale cached h before next stage
    }
}

// ---------------------------------------------------------------------------
extern "C" void kernel_launch(void* const* d_in, const int* in_sizes, int n_in,
                              void* d_out, int out_size, void* d_ws, size_t ws_size,
                              hipStream_t stream) {
    const float* x    = (const float*)d_in[0];
    const float* h0   = (const float*)d_in[1];
    const float* w_ih = (const float*)d_in[2];
    const float* w_hh = (const float*)d_in[3];
    const float* b_ih = (const float*)d_in[4];
    const float* b_hh = (const float*)d_in[5];
    float* out = (float*)d_out;

    // ws layout (all 16B-aligned offsets)
    char* p = (char*)d_ws;
    float* wT_ih = (float*)p;                 p += (size_t)I_SZ * G_SZ * 4;   // 1.5 MB
    f16*   wf16  = (f16*)p;                   p += (size_t)NHS * GB * H_SZ * 2; // 1.5 MB
    f16*   hbuf0 = (f16*)p;                   p += (size_t)B_SZ * H_SZ * 2;   // 128 KB
    f16*   hbuf1 = (f16*)p;                   p += (size_t)B_SZ * H_SZ * 2;   // 128 KB
    unsigned int* ctr = (unsigned int*)p;     p += (size_t)NBS * 32 * 4;      // 1 KB
    float* gi = (float*)p;                    // 805 MB (ws proven >= 810 MB)

    setup_kernel<<<512, 256, 0, stream>>>(w_ih, w_hh, h0, wT_ih, wf16, hbuf0, ctr);

    dim3 pgrid(T_SEQ * B_SZ / 64, G_SZ / 64);   // (2048, 24)
    proj_kernel<<<pgrid, 256, 0, stream>>>(x, wT_ih, b_ih, gi, 0);

    gru_persist<<<NBS * NHS, NTHR, 0, stream>>>(gi, wf16, h0, b_hh,
                                                hbuf0, hbuf1, ctr, out);
}

// Round 3
// 4081.076 us; speedup vs baseline: 8.9320x; 7.5489x over previous
//
#include <hip/hip_runtime.h>
#include <math.h>

#define T_SEQ 1024
#define B_SZ  128
#define I_SZ  256
#define H_SZ  512
#define G_SZ  1536  // 3*H

#define NBS   8    // batch slices (cluster id)
#define MB    16   // batch per block
#define NHS   16   // h slices = blocks per cluster
#define HB    32   // h cols per block
#define GB    96   // gate cols per block (3*HB)
#define NTHR  384  // 6 waves
#define CLUSTER 16

typedef _Float16 f16;
typedef _Float16 half8 __attribute__((ext_vector_type(8)));
typedef float f32x4 __attribute__((ext_vector_type(4)));

// --- coherent (MALL-level) memory ops: bypass L1/L2 so no cache-maintenance
// fences are ever needed for the cross-block h exchange -----------------------
__device__ __forceinline__ f32x4 load_f4_cohere(const void* p) {
    f32x4 v;
    asm volatile("global_load_dwordx4 %0, %1, off sc0 sc1"
                 : "=v"(v) : "v"(p) : "memory");
    return v;
}
__device__ __forceinline__ void store_u32_cohere(void* p, unsigned v) {
    asm volatile("global_store_dword %0, %1, off sc0 sc1"
                 :: "v"(p), "v"(v) : "memory");
}
__device__ __forceinline__ void wait_vm0() {
    asm volatile("s_waitcnt vmcnt(0)" ::: "memory");
    __builtin_amdgcn_sched_barrier(0);
}

// ---------------------------------------------------------------------------
// Setup: wT_ih f32 [I][G] for proj; w_hh -> f16 slices [hs][GB][512] (k-contig);
// h0 -> f16 broadcast; zero cluster counters.
// ---------------------------------------------------------------------------
__global__ void setup_kernel(const float* __restrict__ w_ih,
                             const float* __restrict__ w_hh,
                             const float* __restrict__ h0,
                             float* __restrict__ wT_ih,
                             f16* __restrict__ wf16,
                             f16* __restrict__ hbuf0,
                             unsigned int* __restrict__ ctr) {
    const int i0 = blockIdx.x * blockDim.x + threadIdx.x;
    const int stride = gridDim.x * blockDim.x;
    for (int i = i0; i < I_SZ * G_SZ; i += stride) {
        int g = i / I_SZ, k = i % I_SZ;
        wT_ih[k * G_SZ + g] = w_ih[i];
    }
    for (int i = i0; i < NHS * GB * H_SZ; i += stride) {
        int hs  = i / (GB * H_SZ);
        int rem = i % (GB * H_SZ);
        int gl = rem / H_SZ, k = rem % H_SZ;
        int gate = gl >> 5, c = gl & 31;
        int gg = gate * H_SZ + hs * HB + c;
        wf16[i] = (f16)w_hh[(size_t)gg * H_SZ + k];
    }
    for (int i = i0; i < B_SZ * H_SZ; i += stride) {
        hbuf0[i] = (f16)h0[i % H_SZ];
    }
    if (i0 < NBS * 32) ctr[i0] = 0;
}

// ---------------------------------------------------------------------------
// Input projection GEMM (f32). Writes gi TRANSPOSED: gi[t][g][b].
// ---------------------------------------------------------------------------
__global__ __launch_bounds__(256)
void proj_kernel(const float* __restrict__ x,
                 const float* __restrict__ wT_ih,
                 const float* __restrict__ b_ih,
                 float* __restrict__ gi) {
    const int m0 = blockIdx.x * 64;          // m = t*128 + b
    const int n0 = blockIdx.y * 64;
    const int tid = threadIdx.x;
    const int tx = tid & 15;
    const int ty = tid >> 4;

    __shared__ float As[16][64];
    __shared__ float Bs[16][64];

    float acc[4][4] = {};

    for (int k0 = 0; k0 < I_SZ; k0 += 16) {
        {
            int m  = tid >> 2;
            int kq = (tid & 3) * 4;
            int mm = m0 + m;
            int b  = mm & (B_SZ - 1);
            int t  = mm >> 7;
            const float* arow = x + ((size_t)b * T_SEQ + t) * I_SZ + k0 + kq;
            float4 v = *reinterpret_cast<const float4*>(arow);
            As[kq + 0][m] = v.x; As[kq + 1][m] = v.y;
            As[kq + 2][m] = v.z; As[kq + 3][m] = v.w;
        }
        {
            int k = tid >> 4;
            int n = (tid & 15) * 4;
            float4 v = *reinterpret_cast<const float4*>(
                wT_ih + (size_t)(k0 + k) * G_SZ + n0 + n);
            *reinterpret_cast<float4*>(&Bs[k][n]) = v;
        }
        __syncthreads();
        #pragma unroll
        for (int kk = 0; kk < 16; ++kk) {
            float a[4], bb[4];
            #pragma unroll
            for (int i = 0; i < 4; ++i) a[i] = As[kk][ty * 4 + i];
            #pragma unroll
            for (int j = 0; j < 4; ++j) bb[j] = Bs[kk][tx * 4 + j];
            #pragma unroll
            for (int i = 0; i < 4; ++i)
                #pragma unroll
                for (int j = 0; j < 4; ++j)
                    acc[i][j] = fmaf(a[i], bb[j], acc[i][j]);
        }
        __syncthreads();
    }

    // transposed store: gi[t][n][b], 4 consecutive b per float4
    const int n  = n0 + tx * 4;
    const int t  = m0 >> 7;
    const int b0 = (m0 & (B_SZ - 1)) + ty * 4;
    float4 bv = *reinterpret_cast<const float4*>(b_ih + n);
    float bias[4] = {bv.x, bv.y, bv.z, bv.w};
    #pragma unroll
    for (int j = 0; j < 4; ++j) {
        float4 v;
        v.x = acc[0][j] + bias[j];
        v.y = acc[1][j] + bias[j];
        v.z = acc[2][j] + bias[j];
        v.w = acc[3][j] + bias[j];
        *reinterpret_cast<float4*>(gi + ((size_t)t * G_SZ + n + j) * B_SZ + b0) = v;
    }
}

// ---------------------------------------------------------------------------
// Persistent GRU recurrence. 128 blocks = 8 batch-slices x 16 h-slices.
// Weights live in 64 VGPRs/lane (B fragments, loaded once). h exchanged via
// sc0|sc1 (MALL-coherent) loads/stores; barrier = vmcnt(0) + relaxed agent
// atomic counter. NO cache-maintenance fences anywhere in the loop.
// ---------------------------------------------------------------------------
__global__ __launch_bounds__(NTHR, 1)
void gru_persist(const float* __restrict__ gi,     // [T][G][B]
                 const f16* __restrict__ wf16,     // [NHS][GB][512]
                 const float* __restrict__ h0,
                 const float* __restrict__ b_hh,
                 f16* __restrict__ hbuf0,
                 f16* __restrict__ hbuf1,
                 unsigned int* __restrict__ ctr,
                 float* __restrict__ out) {
    const int bs  = blockIdx.x & (NBS - 1);
    const int hs  = blockIdx.x >> 3;
    const int tid = threadIdx.x;

    __shared__ __align__(16) unsigned char h_lds[MB * H_SZ * 2];  // 16 KB
    __shared__ float act_r[MB][HB + 1];
    __shared__ float act_z[MB][HB + 1];
    __shared__ float act_n[MB][HB + 1];
    __shared__ float act_i[MB][HB + 1];

    const int wid  = tid >> 6;
    const int lane = tid & 63;
    const int gate = wid >> 1;          // 0=r, 1=z, 2=n
    const int sub  = wid & 1;
    const int col  = lane & 15;         // MFMA n / m index
    const int krow = lane >> 4;         // 0..3
    const int c_local = sub * 16 + col;               // 0..31
    const int g_glob  = gate * H_SZ + hs * HB + c_local;

    // ---- B fragments in registers: 16 K-tiles x 4 VGPR = 64 VGPR/lane ----
    half8 bfrag[16];
    {
        const f16* wp = wf16 + ((size_t)hs * GB + gate * HB + c_local) * H_SZ
                             + krow * 8;
        #pragma unroll
        for (int kk = 0; kk < 16; ++kk)
            bfrag[kk] = *reinterpret_cast<const half8*>(wp + kk * 32);
    }
    const float bias = b_hh[g_glob];

    // combine-phase ownership (tid<256): batch row cb, col pair (cc, cc+1)
    const int cb = tid >> 4;
    const int cc = (tid & 15) * 2;
    float hm0 = 0.f, hm1 = 0.f;
    if (tid < 256) { hm0 = h0[hs * HB + cc]; hm1 = h0[hs * HB + cc + 1]; }

    // A-fragment LDS addressing (XOR-swizzled [b][k] f16)
    const unsigned a_base = (unsigned)(col * 1024 + krow * 16);
    const unsigned a_swz  = ((unsigned)(col & 7)) << 4;

    unsigned int* myctr = ctr + bs * 32;

    for (int t = 0; t < T_SEQ; ++t) {
        const f16* hin = (t & 1) ? hbuf1 : hbuf0;
        f16*      hout = (t & 1) ? hbuf0 : hbuf1;

        // gi: one dwordx4 per lane = 4 batch rows of this lane's gate column
        f32x4 giv = *reinterpret_cast<const f32x4*>(
            gi + ((size_t)t * G_SZ + g_glob) * B_SZ + bs * MB + krow * 4);
        float ga[4] = {giv[0], giv[1], giv[2], giv[3]};

        // ---- stage h (16 KB) via MALL-coherent loads ----
        {
            const int i0 = tid, i1 = tid + NTHR, i2 = tid + 2 * NTHR;
            f32x4 hv0 = load_f4_cohere(
                hin + (size_t)(bs * MB + (i0 >> 6)) * H_SZ + (i0 & 63) * 8);
            f32x4 hv1 = load_f4_cohere(
                hin + (size_t)(bs * MB + (i1 >> 6)) * H_SZ + (i1 & 63) * 8);
            f32x4 hv2;
            if (i2 < 1024)
                hv2 = load_f4_cohere(
                    hin + (size_t)(bs * MB + (i2 >> 6)) * H_SZ + (i2 & 63) * 8);
            wait_vm0();
            {
                unsigned a0 = ((unsigned)((i0 >> 6) * 1024 + (i0 & 63) * 16))
                              ^ (((unsigned)((i0 >> 6) & 7)) << 4);
                *reinterpret_cast<f32x4*>(h_lds + a0) = hv0;
                unsigned a1 = ((unsigned)((i1 >> 6) * 1024 + (i1 & 63) * 16))
                              ^ (((unsigned)((i1 >> 6) & 7)) << 4);
                *reinterpret_cast<f32x4*>(h_lds + a1) = hv1;
                if (i2 < 1024) {
                    unsigned a2 = ((unsigned)((i2 >> 6) * 1024 + (i2 & 63) * 16))
                                  ^ (((unsigned)((i2 >> 6) & 7)) << 4);
                    *reinterpret_cast<f32x4*>(h_lds + a2) = hv2;
                }
            }
        }
        __syncthreads();

        // ---- gh tile: 16 batch x 16 cols, K=512, B from registers ----
        f32x4 acc = {0.f, 0.f, 0.f, 0.f};
        #pragma unroll
        for (int kk = 0; kk < 16; ++kk) {
            half8 av = *reinterpret_cast<const half8*>(
                h_lds + ((a_base + kk * 64) ^ a_swz));
            acc = __builtin_amdgcn_mfma_f32_16x16x32_f16(av, bfrag[kk], acc, 0, 0, 0);
        }

        // ---- per-gate activation to LDS ----
        if (gate == 0) {
            #pragma unroll
            for (int r = 0; r < 4; ++r)
                act_r[krow * 4 + r][c_local] =
                    1.f / (1.f + __expf(-(acc[r] + bias + ga[r])));
        } else if (gate == 1) {
            #pragma unroll
            for (int r = 0; r < 4; ++r)
                act_z[krow * 4 + r][c_local] =
                    1.f / (1.f + __expf(-(acc[r] + bias + ga[r])));
        } else {
            #pragma unroll
            for (int r = 0; r < 4; ++r) {
                act_n[krow * 4 + r][c_local] = acc[r] + bias;  // hn pre-act
                act_i[krow * 4 + r][c_local] = ga[r];          // inn
            }
        }
        __syncthreads();

        // ---- combine: thread owns (cb, cc..cc+1) ----
        if (tid < 256) {
            float r0 = act_r[cb][cc],     r1 = act_r[cb][cc + 1];
            float z0 = act_z[cb][cc],     z1 = act_z[cb][cc + 1];
            float a0 = act_i[cb][cc]     + r0 * act_n[cb][cc];
            float a1 = act_i[cb][cc + 1] + r1 * act_n[cb][cc + 1];
            float n0 = 1.f - 2.f / (__expf(2.f * a0) + 1.f);
            float n1 = 1.f - 2.f / (__expf(2.f * a1) + 1.f);
            float hn0 = (1.f - z0) * n0 + z0 * hm0;
            float hn1 = (1.f - z1) * n1 + z1 * hm1;
            hn0 = fminf(fmaxf(hn0, -5.f), 5.f);
            hn1 = fminf(fmaxf(hn1, -5.f), 5.f);
            hm0 = hn0; hm1 = hn1;

            const int bg = bs * MB + cb;
            const int hg = hs * HB + cc;
            *reinterpret_cast<float2*>(
                out + ((size_t)bg * T_SEQ + t) * H_SZ + hg) = make_float2(hn0, hn1);

            f16 p0 = (f16)hn0, p1 = (f16)hn1;
            unsigned pack = (unsigned)__builtin_bit_cast(unsigned short, p0)
                          | ((unsigned)__builtin_bit_cast(unsigned short, p1) << 16);
            store_u32_cohere(hout + (size_t)bg * H_SZ + hg, pack);

            if (t == T_SEQ - 1)
                *reinterpret_cast<float2*>(
                    out + (size_t)B_SZ * T_SEQ * H_SZ + (size_t)bg * H_SZ + hg) =
                    make_float2(hn0, hn1);
        }

        // ---- cluster barrier: vmcnt-drain + relaxed agent atomic ----
        wait_vm0();          // sc1 h stores (and out stores) complete
        __syncthreads();     // all waves' stores drained before tid0 signals
        if (tid == 0) {
            __hip_atomic_fetch_add(myctr, 1u, __ATOMIC_RELAXED,
                                   __HIP_MEMORY_SCOPE_AGENT);
            const unsigned target = (unsigned)(CLUSTER * (t + 1));
            long guard = 0;
            while (__hip_atomic_load(myctr, __ATOMIC_RELAXED,
                                     __HIP_MEMORY_SCOPE_AGENT) < target) {
                __builtin_amdgcn_s_sleep(1);
                if (++guard > (1L << 24)) break;   // safety escape
            }
        }
        __syncthreads();
    }
}

// ---------------------------------------------------------------------------
extern "C" void kernel_launch(void* const* d_in, const int* in_sizes, int n_in,
                              void* d_out, int out_size, void* d_ws, size_t ws_size,
                              hipStream_t stream) {
    const float* x    = (const float*)d_in[0];
    const float* h0   = (const float*)d_in[1];
    const float* w_ih = (const float*)d_in[2];
    const float* w_hh = (const float*)d_in[3];
    const float* b_ih = (const float*)d_in[4];
    const float* b_hh = (const float*)d_in[5];
    float* out = (float*)d_out;

    char* p = (char*)d_ws;
    float* wT_ih = (float*)p;             p += (size_t)I_SZ * G_SZ * 4;
    f16*   wf16  = (f16*)p;               p += (size_t)NHS * GB * H_SZ * 2;
    f16*   hbuf0 = (f16*)p;               p += (size_t)B_SZ * H_SZ * 2;
    f16*   hbuf1 = (f16*)p;               p += (size_t)B_SZ * H_SZ * 2;
    unsigned int* ctr = (unsigned int*)p; p += (size_t)NBS * 32 * 4;
    float* gi = (float*)p;                // [T][G][B] f32, 805 MB (ws proven OK)

    setup_kernel<<<512, 256, 0, stream>>>(w_ih, w_hh, h0, wT_ih, wf16, hbuf0, ctr);

    dim3 pgrid(T_SEQ * B_SZ / 64, G_SZ / 64);   // (2048, 24)
    proj_kernel<<<pgrid, 256, 0, stream>>>(x, wT_ih, b_ih, gi);

    gru_persist<<<NBS * NHS, NTHR, 0, stream>>>(gi, wf16, h0, b_hh,
                                                hbuf0, hbuf1, ctr, out);
}